// Round 12
// baseline (215.518 us; speedup 1.0000x reference)
//
#include <hip/hip_runtime.h>
#include <math.h>

// B=64, T=512, C=384, H=64. fp32 in/out; bf16 MFMA internally.
#define NB 64
#define NT 512
#define NC 384
#define NH 64

typedef __attribute__((ext_vector_type(8))) short bf16x8;
typedef __attribute__((ext_vector_type(4))) float f32x4;

__device__ __forceinline__ unsigned short f2bf(float f) {
  unsigned int u = __float_as_uint(f);
  return (unsigned short)((u + 0x7FFFu + ((u >> 16) & 1u)) >> 16);
}
__device__ __forceinline__ unsigned int pk2bf(float a, float b) {
  return (unsigned int)f2bf(a) | ((unsigned int)f2bf(b) << 16);
}

// Device-scope grid barrier: 256 co-resident blocks (grid==256 <= CU count,
// so all blocks are resident by construction -> no deadlock).
__device__ __forceinline__ void grid_barrier(unsigned* cnt) {
  __syncthreads();
  if (threadIdx.x == 0) {
    __threadfence();                      // release: drain this block's writes
    atomicAdd(cnt, 1u);
    while (atomicAdd(cnt, 0u) < 256u) __builtin_amdgcn_s_sleep(8);
  }
  __syncthreads();
  __threadfence();                        // acquire for all waves of the block
}

#define XS 392   // proj x-tile row stride (ushorts)
#define PSTR 72  // attn P round-trip row stride (ushorts)

// ---------------------------------------------------------------------------
// Persistent fused kernel. 256 blocks x 384 threads (6 waves).
// Phase 0: W transpose -> barrier -> Phase 1: proj (r7 form, 2 tiles/block,
// wave-resident B-frags loaded ONCE -> half the Wt traffic) -> barrier ->
// Phase 2: attn (r7 form), wave gw handles q-tiles gw and gw+1536.
// ---------------------------------------------------------------------------
__global__ __launch_bounds__(384, 2) void fused_kernel(
    const float* __restrict__ x, const float* __restrict__ Wq,
    const float* __restrict__ Wk, const float* __restrict__ Wv,
    unsigned* __restrict__ cnt, unsigned short* __restrict__ Wt,
    unsigned short* __restrict__ q, unsigned short* __restrict__ k,
    unsigned short* __restrict__ vt, float* __restrict__ out) {
  __shared__ unsigned short xs[64 * XS];  // 50176 B; aliased as ps in phase 2
  const int bx = blockIdx.x;
  const int t = threadIdx.x;  // 0..383
  const int w = t / 64, l = t & 63, mi = l & 15, quad = l >> 4;

  // ---- phase 0: W[c][h] fp32 -> Wt[(m*64+h)][c] bf16 ----
  {
    int id = bx * 384 + t;  // 98304 threads >= 73728 elems
    if (id < 3 * NC * NH) {
      int m = id / (NC * NH);
      int r = id % (NC * NH);
      int c = r / NH;
      int h = r % NH;
      const float* W = (m == 0) ? Wq : ((m == 1) ? Wk : Wv);
      Wt[(m * NH + h) * NC + c] = f2bf(W[c * NH + h]);
    }
  }
  grid_barrier(cnt);

  // ---- phase 1: QKV projection, rows bx*128 .. +127 (two 64-row tiles) ----
  {
    // wave-resident B-frags: tiles 2w, 2w+1 — loaded once, reused both halves
    bf16x8 bfr[2][12];
#pragma unroll
    for (int ntl = 0; ntl < 2; ++ntl) {
      const unsigned short* wr =
          Wt + (size_t)((w * 2 + ntl) * 16 + mi) * NC + quad * 8;
#pragma unroll
      for (int kc = 0; kc < 12; ++kc)
        bfr[ntl][kc] = *(const bf16x8*)(wr + kc * 32);
    }

    for (int half = 0; half < 2; ++half) {
      const int m0 = bx * 128 + half * 64;
      if (half) __syncthreads();  // prior half's xs reads complete

      // stage x tile: 64 rows x 384 fp32 -> bf16 (coalesced float4)
#pragma unroll 4
      for (int i = 0; i < 16; ++i) {
        int u = t + i * 384;
        int row = u / 96;
        int cp = (u % 96) * 4;
        float4 a = *(const float4*)(x + (size_t)(m0 + row) * NC + cp);
        ushort4 bb;
        bb.x = f2bf(a.x); bb.y = f2bf(a.y); bb.z = f2bf(a.z); bb.w = f2bf(a.w);
        *(ushort4*)&xs[row * XS + cp] = bb;
      }
      __syncthreads();

      f32x4 acc[2][4];  // [ntl][msub]
      const f32x4 zero = {0.f, 0.f, 0.f, 0.f};
#pragma unroll
      for (int i = 0; i < 2; ++i)
#pragma unroll
        for (int j = 0; j < 4; ++j) acc[i][j] = zero;

#pragma unroll
      for (int msub = 0; msub < 4; ++msub) {
#pragma unroll
        for (int kc = 0; kc < 12; ++kc) {
          bf16x8 a =
              *(const bf16x8*)&xs[(msub * 16 + mi) * XS + kc * 32 + quad * 8];
          acc[0][msub] = __builtin_amdgcn_mfma_f32_16x16x32_bf16(
              a, bfr[0][kc], acc[0][msub], 0, 0, 0);
          acc[1][msub] = __builtin_amdgcn_mfma_f32_16x16x32_bf16(
              a, bfr[1][kc], acc[1][msub], 0, 0, 0);
        }
      }

      // epilogue: C/D col=mi, row=quad*4+r. Tile=2w+ntl; matrix=tile>>2.
      if (w < 4) {
        unsigned short* dst = (w < 2) ? q : k;
        const float sc = (w < 2) ? 0.125f : 1.0f;  // fold 1/sqrt(64), exact
#pragma unroll
        for (int ntl = 0; ntl < 2; ++ntl) {
          int tile = w * 2 + ntl;
          int h = (tile & 3) * 16 + mi;
#pragma unroll
          for (int msub = 0; msub < 4; ++msub)
#pragma unroll
            for (int r = 0; r < 4; ++r)
              dst[(size_t)(m0 + msub * 16 + quad * 4 + r) * NH + h] =
                  f2bf(acc[ntl][msub][r] * sc);
        }
      } else {  // v: 4 consecutive tokens per lane -> ushort4 into vt[b][h][t]
        int bb = m0 >> 9, t0 = m0 & 511;
#pragma unroll
        for (int ntl = 0; ntl < 2; ++ntl) {
          int tile = w * 2 + ntl;
          int h = (tile & 3) * 16 + mi;
#pragma unroll
          for (int msub = 0; msub < 4; ++msub) {
            ushort4 s;
            s.x = f2bf(acc[ntl][msub][0]);
            s.y = f2bf(acc[ntl][msub][1]);
            s.z = f2bf(acc[ntl][msub][2]);
            s.w = f2bf(acc[ntl][msub][3]);
            *(ushort4*)&vt[((size_t)bb * NH + h) * NT + t0 + msub * 16 +
                           quad * 4] = s;
          }
        }
      }
    }
  }
  grid_barrier(cnt + 1);

  // ---- phase 2: causal flash attention (r7 form), wave-per-q-tile ----
  {
    unsigned short* ps = &xs[w * 16 * PSTR];  // wave-private LDS (aliased)
    const int gw = bx * 6 + w;                // 0..1535
    const f32x4 zero = {0.f, 0.f, 0.f, 0.f};

    for (int pass = 0; pass < 2; ++pass) {
      const int ti = gw + pass * 1536;
      if (ti >= 2048) break;
      const int qi = 31 - (ti >> 6);  // heavy tiles first
      const int b = ti & 63;

      const unsigned short* qrow = q + ((size_t)b * NT + qi * 16 + mi) * NH;
      bf16x8 qb0 = *(const bf16x8*)(qrow + quad * 8);
      bf16x8 qb1 = *(const bf16x8*)(qrow + 32 + quad * 8);

      f32x4 accO[4];
#pragma unroll
      for (int i = 0; i < 4; ++i) accO[i] = zero;
      float mrow = -INFINITY, lrow = 0.f;  // per-lane q-row = qi*16 + mi

      const int ktmax = (qi * 16 + 15) >> 6;
      for (int kt = 0; kt <= ktmax; ++kt) {
        const unsigned short* kb = k + ((size_t)b * NT + kt * 64) * NH;
        const unsigned short* vb = vt + (size_t)b * NH * NT + kt * 64;
        bf16x8 ka0[4], ka1[4], va0[4], va1[4];
#pragma unroll
        for (int nt = 0; nt < 4; ++nt) {
          const unsigned short* kr = kb + (size_t)(nt * 16 + mi) * NH + quad * 8;
          ka0[nt] = *(const bf16x8*)kr;
          ka1[nt] = *(const bf16x8*)(kr + 32);
          const unsigned short* vr = vb + (size_t)(nt * 16 + mi) * NT + quad * 8;
          va0[nt] = *(const bf16x8*)vr;
          va1[nt] = *(const bf16x8*)(vr + 32);
        }

        // S^T tile: A = K rows (m=key), B = Q rows (n=q).
        float p[4][4];
#pragma unroll
        for (int nt = 0; nt < 4; ++nt) {
          f32x4 z = zero;
          z = __builtin_amdgcn_mfma_f32_16x16x32_bf16(ka0[nt], qb0, z, 0, 0, 0);
          z = __builtin_amdgcn_mfma_f32_16x16x32_bf16(ka1[nt], qb1, z, 0, 0, 0);
#pragma unroll
          for (int r = 0; r < 4; ++r) p[nt][r] = z[r];
        }

        if (kt == ktmax) {  // causal mask on diagonal tile
#pragma unroll
          for (int nt = 0; nt < 4; ++nt)
#pragma unroll
            for (int r = 0; r < 4; ++r)
              if (kt * 64 + nt * 16 + quad * 4 + r > qi * 16 + mi)
                p[nt][r] = -INFINITY;
        }

        // online softmax for q=mi (keys spread across quads)
        float vmax = -INFINITY;
#pragma unroll
        for (int nt = 0; nt < 4; ++nt)
#pragma unroll
          for (int r = 0; r < 4; ++r) vmax = fmaxf(vmax, p[nt][r]);
        vmax = fmaxf(vmax, __shfl_xor(vmax, 16));
        vmax = fmaxf(vmax, __shfl_xor(vmax, 32));
        float mn = fmaxf(mrow, vmax);
        float alpha = __expf(mrow - mn);
        mrow = mn;

        float rsum = 0.f;
#pragma unroll
        for (int nt = 0; nt < 4; ++nt)
#pragma unroll
          for (int r = 0; r < 4; ++r) {
            p[nt][r] = __expf(p[nt][r] - mn);
            rsum += p[nt][r];
          }
        rsum += __shfl_xor(rsum, 16);
        rsum += __shfl_xor(rsum, 32);
        lrow = lrow * alpha + rsum;

        // P -> LDS (row-contiguous, wave-local, no barrier) -> A-frags
#pragma unroll
        for (int nt = 0; nt < 4; ++nt) {
          uint2 pk;
          pk.x = pk2bf(p[nt][0], p[nt][1]);
          pk.y = pk2bf(p[nt][2], p[nt][3]);
          *(uint2*)&ps[mi * PSTR + nt * 16 + quad * 4] = pk;
        }
        bf16x8 pa0 = *(const bf16x8*)&ps[mi * PSTR + quad * 8];
        bf16x8 pa1 = *(const bf16x8*)&ps[mi * PSTR + 32 + quad * 8];

        float av[4];
#pragma unroll
        for (int r = 0; r < 4; ++r) av[r] = __shfl(alpha, quad * 4 + r);
#pragma unroll
        for (int hi = 0; hi < 4; ++hi)
#pragma unroll
          for (int r = 0; r < 4; ++r) accO[hi][r] *= av[r];

        // O += P V  (A = P rows, B = V^T rows; D col=h, row=q)
#pragma unroll
        for (int hi = 0; hi < 4; ++hi) {
          accO[hi] = __builtin_amdgcn_mfma_f32_16x16x32_bf16(pa0, va0[hi],
                                                             accO[hi], 0, 0, 0);
          accO[hi] = __builtin_amdgcn_mfma_f32_16x16x32_bf16(pa1, va1[hi],
                                                             accO[hi], 0, 0, 0);
        }
      }

      float inv = 1.f / lrow;
      const size_t obase = ((size_t)b * NT + qi * 16) * NH;
#pragma unroll
      for (int r = 0; r < 4; ++r) {
        float iv = __shfl(inv, quad * 4 + r);
#pragma unroll
        for (int hi = 0; hi < 4; ++hi)
          out[obase + (size_t)(quad * 4 + r) * NH + hi * 16 + mi] =
              accO[hi][r] * iv;
      }
    }
  }
}

extern "C" void kernel_launch(void* const* d_in, const int* in_sizes, int n_in,
                              void* d_out, int out_size, void* d_ws, size_t ws_size,
                              hipStream_t stream) {
  const float* x  = (const float*)d_in[0];
  const float* Wq = (const float*)d_in[1];
  const float* Wk = (const float*)d_in[2];
  const float* Wv = (const float*)d_in[3];

  unsigned* cnt = (unsigned*)d_ws;                     // 2 barrier counters
  unsigned short* Wt = (unsigned short*)d_ws + 128;    // 256 B offset; 192*384
  unsigned short* qb = Wt + 192 * 384;                 // 32768*64 each
  unsigned short* kb = qb + 32768 * 64;
  unsigned short* vtb = kb + 32768 * 64;               // Vt[b][h][t]
  float* out = (float*)d_out;

  hipMemsetAsync(cnt, 0, 8, stream);  // zero the barrier counters (capturable)
  fused_kernel<<<256, 384, 0, stream>>>(x, Wq, Wk, Wv, cnt, Wt, qb, kb, vtb, out);
}